// Round 1
// baseline (142.950 us; speedup 1.0000x reference)
//
#include <hip/hip_runtime.h>
#include <hip/hip_bf16.h>

// SpMM: out[r] = sum_e (rows[e]==r) vals[e] * x[cols[e], :]
// rows sorted ascending (CSR-like). N=100000 nodes, E=1600000 edges, D=48.
//
// Plan:
//  1) build_row_ptr: row_ptr[r] = lower_bound(rows, r) via binary search
//     (row_ptr lives in d_ws; rebuilt every launch since ws is re-poisoned).
//  2) spmm_rows: 12 threads per row (float4 feature slice each, 48=12*4),
//     16 rows per 192-thread block. Atomic-free; every row written once.

#define D_FEAT 48
#define TPR 12          // threads per row (each owns a float4 slice)
#define RPB 16          // rows per block
#define BLOCK (TPR * RPB)  // 192

__global__ void build_row_ptr(const int* __restrict__ rows,
                              int* __restrict__ row_ptr,
                              int n_edges, int n_nodes) {
    int r = blockIdx.x * blockDim.x + threadIdx.x;
    if (r > n_nodes) return;
    // first index i with rows[i] >= r
    int lo = 0, hi = n_edges;
    while (lo < hi) {
        int mid = (lo + hi) >> 1;
        if (rows[mid] < r) lo = mid + 1; else hi = mid;
    }
    row_ptr[r] = lo;
}

__global__ __launch_bounds__(BLOCK) void spmm_rows(
        const int* __restrict__ row_ptr,
        const int* __restrict__ cols,
        const float* __restrict__ vals,
        const float* __restrict__ x,
        float* __restrict__ out,
        int n_nodes) {
    const int tid = threadIdx.x;
    const int fg  = tid % TPR;           // feature group: floats [4*fg, 4*fg+4)
    const int rib = tid / TPR;           // row within block
    const int r   = blockIdx.x * RPB + rib;
    if (r >= n_nodes) return;

    const int e0 = row_ptr[r];
    const int e1 = row_ptr[r + 1];

    float4 acc = make_float4(0.f, 0.f, 0.f, 0.f);

    int e = e0;
    // 2-edge unroll: two independent gather chains in flight per thread.
    for (; e + 1 < e1; e += 2) {
        const int   c0 = cols[e];
        const int   c1 = cols[e + 1];
        const float v0 = vals[e];
        const float v1 = vals[e + 1];
        const float4 xa = *reinterpret_cast<const float4*>(
            x + (size_t)c0 * D_FEAT + fg * 4);
        const float4 xb = *reinterpret_cast<const float4*>(
            x + (size_t)c1 * D_FEAT + fg * 4);
        acc.x += v0 * xa.x + v1 * xb.x;
        acc.y += v0 * xa.y + v1 * xb.y;
        acc.z += v0 * xa.z + v1 * xb.z;
        acc.w += v0 * xa.w + v1 * xb.w;
    }
    if (e < e1) {
        const int   c0 = cols[e];
        const float v0 = vals[e];
        const float4 xa = *reinterpret_cast<const float4*>(
            x + (size_t)c0 * D_FEAT + fg * 4);
        acc.x += v0 * xa.x;
        acc.y += v0 * xa.y;
        acc.z += v0 * xa.z;
        acc.w += v0 * xa.w;
    }

    *reinterpret_cast<float4*>(out + (size_t)r * D_FEAT + fg * 4) = acc;
}

extern "C" void kernel_launch(void* const* d_in, const int* in_sizes, int n_in,
                              void* d_out, int out_size, void* d_ws, size_t ws_size,
                              hipStream_t stream) {
    // inputs: t(f32,1), x(f32,N*48), rows(i32,E), cols(i32,E), vals(f32,E)
    const float* x    = (const float*)d_in[1];
    const int*   rows = (const int*)  d_in[2];
    const int*   cols = (const int*)  d_in[3];
    const float* vals = (const float*)d_in[4];
    float*       out  = (float*)d_out;

    const int n_edges = in_sizes[2];
    const int n_nodes = out_size / D_FEAT;   // 100000

    int* row_ptr = (int*)d_ws;               // (n_nodes+1) ints

    {
        const int threads = 256;
        const int grid = (n_nodes + 1 + threads - 1) / threads;
        build_row_ptr<<<grid, threads, 0, stream>>>(rows, row_ptr, n_edges, n_nodes);
    }
    {
        const int grid = (n_nodes + RPB - 1) / RPB;   // 6250
        spmm_rows<<<grid, BLOCK, 0, stream>>>(row_ptr, cols, vals, x, out, n_nodes);
    }
}

// Round 2
// 138.225 us; speedup vs baseline: 1.0342x; 1.0342x over previous
//
#include <hip/hip_runtime.h>
#include <hip/hip_bf16.h>

// SpMM: out[r] = sum_e (rows[e]==r) vals[e] * x[cols[e], :]
// rows sorted ascending (CSR-like). N=100000 nodes, E=1600000 edges, D=48.
//
//  1) build_row_ptr_scatter: rows sorted -> each edge e writes row_ptr[q]=e
//     for q in (rows[e-1], rows[e]]. One coalesced pass, ~3us (replaces the
//     85us binary-search version: 21 dependent cache probes/thread was the
//     R1 bottleneck).
//  2) spmm_rows: 12 threads per row (float4 slice each, 48=12*4), 16 rows
//     per 192-thread block, 4-deep edge unroll for gather MLP. Atomic-free.

#define D_FEAT 48
#define TPR 12          // threads per row (each owns a float4 slice)
#define RPB 16          // rows per block
#define BLOCK (TPR * RPB)  // 192

__global__ void build_row_ptr_scatter(const int* __restrict__ rows,
                                      int* __restrict__ row_ptr,
                                      int n_edges, int n_nodes) {
    int e = blockIdx.x * blockDim.x + threadIdx.x;
    if (e >= n_edges) return;
    const int r     = rows[e];
    const int rprev = (e == 0) ? -1 : rows[e - 1];
    // row_ptr[q] = lower_bound(rows, q); for q in (rprev, r] that's e.
    for (int q = rprev + 1; q <= r; ++q) row_ptr[q] = e;
    if (e == n_edges - 1) {
        for (int q = r + 1; q <= n_nodes; ++q) row_ptr[q] = n_edges;
    }
}

__global__ __launch_bounds__(BLOCK) void spmm_rows(
        const int* __restrict__ row_ptr,
        const int* __restrict__ cols,
        const float* __restrict__ vals,
        const float* __restrict__ x,
        float* __restrict__ out,
        int n_nodes) {
    const int tid = threadIdx.x;
    const int fg  = tid % TPR;           // feature group: floats [4*fg, 4*fg+4)
    const int rib = tid / TPR;           // row within block
    const int r   = blockIdx.x * RPB + rib;
    if (r >= n_nodes) return;

    const int e0 = row_ptr[r];
    const int e1 = row_ptr[r + 1];

    float4 acc = make_float4(0.f, 0.f, 0.f, 0.f);

    int e = e0;
    // 4-edge unroll: four independent gather chains in flight per thread.
    for (; e + 3 < e1; e += 4) {
        const int   c0 = cols[e];
        const int   c1 = cols[e + 1];
        const int   c2 = cols[e + 2];
        const int   c3 = cols[e + 3];
        const float v0 = vals[e];
        const float v1 = vals[e + 1];
        const float v2 = vals[e + 2];
        const float v3 = vals[e + 3];
        const float4 xa = *reinterpret_cast<const float4*>(x + (size_t)c0 * D_FEAT + fg * 4);
        const float4 xb = *reinterpret_cast<const float4*>(x + (size_t)c1 * D_FEAT + fg * 4);
        const float4 xc = *reinterpret_cast<const float4*>(x + (size_t)c2 * D_FEAT + fg * 4);
        const float4 xd = *reinterpret_cast<const float4*>(x + (size_t)c3 * D_FEAT + fg * 4);
        acc.x += v0 * xa.x + v1 * xb.x + v2 * xc.x + v3 * xd.x;
        acc.y += v0 * xa.y + v1 * xb.y + v2 * xc.y + v3 * xd.y;
        acc.z += v0 * xa.z + v1 * xb.z + v2 * xc.z + v3 * xd.z;
        acc.w += v0 * xa.w + v1 * xb.w + v2 * xc.w + v3 * xd.w;
    }
    for (; e < e1; ++e) {
        const int   c0 = cols[e];
        const float v0 = vals[e];
        const float4 xa = *reinterpret_cast<const float4*>(x + (size_t)c0 * D_FEAT + fg * 4);
        acc.x += v0 * xa.x;
        acc.y += v0 * xa.y;
        acc.z += v0 * xa.z;
        acc.w += v0 * xa.w;
    }

    *reinterpret_cast<float4*>(out + (size_t)r * D_FEAT + fg * 4) = acc;
}

extern "C" void kernel_launch(void* const* d_in, const int* in_sizes, int n_in,
                              void* d_out, int out_size, void* d_ws, size_t ws_size,
                              hipStream_t stream) {
    // inputs: t(f32,1), x(f32,N*48), rows(i32,E), cols(i32,E), vals(f32,E)
    const float* x    = (const float*)d_in[1];
    const int*   rows = (const int*)  d_in[2];
    const int*   cols = (const int*)  d_in[3];
    const float* vals = (const float*)d_in[4];
    float*       out  = (float*)d_out;

    const int n_edges = in_sizes[2];
    const int n_nodes = out_size / D_FEAT;   // 100000

    int* row_ptr = (int*)d_ws;               // (n_nodes+1) ints

    {
        const int threads = 256;
        const int grid = (n_edges + threads - 1) / threads;
        build_row_ptr_scatter<<<grid, threads, 0, stream>>>(rows, row_ptr, n_edges, n_nodes);
    }
    {
        const int grid = (n_nodes + RPB - 1) / RPB;   // 6250
        spmm_rows<<<grid, BLOCK, 0, stream>>>(row_ptr, cols, vals, x, out, n_nodes);
    }
}

// Round 3
// 128.564 us; speedup vs baseline: 1.1119x; 1.0751x over previous
//
#include <hip/hip_runtime.h>
#include <hip/hip_bf16.h>
#include <hip/hip_fp16.h>

// SpMM: out[r] = sum_e (rows[e]==r) vals[e] * x[cols[e], :]
// rows sorted ascending (CSR-like). N=100000, E=1600000, D=48.
//
// R2 finding: gather is throughput-bound at the L2-miss interface
// (174 MB @ ~3.4 TB/s, VALUBusy 8.5%, unroll 2->4 gave only 4%).
// R3: gather from an fp16 copy of x (built per-launch in d_ws) ->
// halves gather bytes AND more than doubles effective L2 hit rate
// (9.6 MB fp16 x vs 4 MB per-XCD L2). Error budget: fp16 adds ~0.01
// absolute vs 0.3 threshold.

#define D_FEAT 48
#define TPR 12          // threads per row (each owns a 4-feature slice)
#define RPB 16          // rows per block
#define BLOCK (TPR * RPB)  // 192

__global__ void build_row_ptr_scatter(const int* __restrict__ rows,
                                      int* __restrict__ row_ptr,
                                      int n_edges, int n_nodes) {
    int e = blockIdx.x * blockDim.x + threadIdx.x;
    if (e >= n_edges) return;
    const int r     = rows[e];
    const int rprev = (e == 0) ? -1 : rows[e - 1];
    for (int q = rprev + 1; q <= r; ++q) row_ptr[q] = e;
    if (e == n_edges - 1) {
        for (int q = r + 1; q <= n_nodes; ++q) row_ptr[q] = n_edges;
    }
}

__global__ void convert_x_f16(const float* __restrict__ x,
                              __half* __restrict__ xh, int n4) {
    int i = blockIdx.x * blockDim.x + threadIdx.x;
    if (i >= n4) return;
    const float4 f = reinterpret_cast<const float4*>(x)[i];
    union { ushort4 u; __half2 h2[2]; } pk;
    pk.h2[0] = __floats2half2_rn(f.x, f.y);
    pk.h2[1] = __floats2half2_rn(f.z, f.w);
    reinterpret_cast<ushort4*>(xh)[i] = pk.u;
}

__device__ __forceinline__ void fma4_h(float4& acc, float v, const __half* p) {
    union { ushort4 u; __half2 h2[2]; } w;
    w.u = *reinterpret_cast<const ushort4*>(p);       // 8B load
    const float2 f0 = __half22float2(w.h2[0]);
    const float2 f1 = __half22float2(w.h2[1]);
    acc.x += v * f0.x;
    acc.y += v * f0.y;
    acc.z += v * f1.x;
    acc.w += v * f1.y;
}

__global__ __launch_bounds__(BLOCK) void spmm_rows_f16(
        const int* __restrict__ row_ptr,
        const int* __restrict__ cols,
        const float* __restrict__ vals,
        const __half* __restrict__ xh,
        float* __restrict__ out,
        int n_nodes) {
    const int tid = threadIdx.x;
    const int fg  = tid % TPR;
    const int rib = tid / TPR;
    const int r   = blockIdx.x * RPB + rib;
    if (r >= n_nodes) return;

    const int e0 = row_ptr[r];
    const int e1 = row_ptr[r + 1];

    float4 acc = make_float4(0.f, 0.f, 0.f, 0.f);

    int e = e0;
    for (; e + 3 < e1; e += 4) {
        const int   c0 = cols[e];
        const int   c1 = cols[e + 1];
        const int   c2 = cols[e + 2];
        const int   c3 = cols[e + 3];
        const float v0 = vals[e];
        const float v1 = vals[e + 1];
        const float v2 = vals[e + 2];
        const float v3 = vals[e + 3];
        fma4_h(acc, v0, xh + (size_t)c0 * D_FEAT + fg * 4);
        fma4_h(acc, v1, xh + (size_t)c1 * D_FEAT + fg * 4);
        fma4_h(acc, v2, xh + (size_t)c2 * D_FEAT + fg * 4);
        fma4_h(acc, v3, xh + (size_t)c3 * D_FEAT + fg * 4);
    }
    for (; e < e1; ++e) {
        fma4_h(acc, vals[e], xh + (size_t)cols[e] * D_FEAT + fg * 4);
    }

    *reinterpret_cast<float4*>(out + (size_t)r * D_FEAT + fg * 4) = acc;
}

// f32 fallback (used only if ws_size can't hold the fp16 copy)
__global__ __launch_bounds__(BLOCK) void spmm_rows_f32(
        const int* __restrict__ row_ptr,
        const int* __restrict__ cols,
        const float* __restrict__ vals,
        const float* __restrict__ x,
        float* __restrict__ out,
        int n_nodes) {
    const int tid = threadIdx.x;
    const int fg  = tid % TPR;
    const int rib = tid / TPR;
    const int r   = blockIdx.x * RPB + rib;
    if (r >= n_nodes) return;
    const int e0 = row_ptr[r];
    const int e1 = row_ptr[r + 1];
    float4 acc = make_float4(0.f, 0.f, 0.f, 0.f);
    for (int e = e0; e < e1; ++e) {
        const float v = vals[e];
        const float4 xa = *reinterpret_cast<const float4*>(
            x + (size_t)cols[e] * D_FEAT + fg * 4);
        acc.x += v * xa.x; acc.y += v * xa.y;
        acc.z += v * xa.z; acc.w += v * xa.w;
    }
    *reinterpret_cast<float4*>(out + (size_t)r * D_FEAT + fg * 4) = acc;
}

extern "C" void kernel_launch(void* const* d_in, const int* in_sizes, int n_in,
                              void* d_out, int out_size, void* d_ws, size_t ws_size,
                              hipStream_t stream) {
    // inputs: t(f32,1), x(f32,N*48), rows(i32,E), cols(i32,E), vals(f32,E)
    const float* x    = (const float*)d_in[1];
    const int*   rows = (const int*)  d_in[2];
    const int*   cols = (const int*)  d_in[3];
    const float* vals = (const float*)d_in[4];
    float*       out  = (float*)d_out;

    const int n_edges = in_sizes[2];
    const int n_x     = in_sizes[1];           // n_nodes * 48
    const int n_nodes = out_size / D_FEAT;     // 100000

    int* row_ptr = (int*)d_ws;                 // (n_nodes+1) ints
    const size_t rp_bytes  = (size_t)(n_nodes + 1) * sizeof(int);
    const size_t xh_off    = (rp_bytes + 255) & ~(size_t)255;
    const size_t need      = xh_off + (size_t)n_x * sizeof(__half);

    {
        const int threads = 256;
        const int grid = (n_edges + threads - 1) / threads;
        build_row_ptr_scatter<<<grid, threads, 0, stream>>>(rows, row_ptr, n_edges, n_nodes);
    }

    if (ws_size >= need) {
        __half* xh = (__half*)((char*)d_ws + xh_off);
        {
            const int n4 = n_x / 4;
            const int threads = 256;
            const int grid = (n4 + threads - 1) / threads;
            convert_x_f16<<<grid, threads, 0, stream>>>(x, xh, n4);
        }
        const int grid = (n_nodes + RPB - 1) / RPB;
        spmm_rows_f16<<<grid, BLOCK, 0, stream>>>(row_ptr, cols, vals, xh, out, n_nodes);
    } else {
        const int grid = (n_nodes + RPB - 1) / RPB;
        spmm_rows_f32<<<grid, BLOCK, 0, stream>>>(row_ptr, cols, vals, x, out, n_nodes);
    }
}